// Round 6
// baseline (107744.336 us; speedup 1.0000x reference)
//
#include <hip/hip_runtime.h>
#include <cmath>
#include <cfloat>

#define Hdim 768
#define Bb 32
#define Kb 5
#define Ss 64
#define Vv 30522
#define Tt 40
#define SEPTOK 102
#define PC 16

typedef __attribute__((ext_vector_type(2))) double f64x2;
typedef __attribute__((ext_vector_type(2))) float  f32x2;
typedef __attribute__((ext_vector_type(4))) float  f32x4;

// ---------------------------------------------------------------------------
// fp64-accumulate GEMM, LDS-staged X (exact f64) + LDS-transposed W tile:
//   out[n,i] = f32( sum_p (f64)X[n*xrs+p] * (f64)W_elem(p,i) )  (+bias, f32)
// W_elem(p,i) = PMAJOR ? W[p*ld + i] : W[i*ld + p]  (both read COALESCED).
// Block: 256 thr, tile = 16 rows x (256*CPT) cols, K-chunk = PC(16).
// N multiple of 16; P multiple of 16. Accumulation: sequential in p per
// thread (true-f64 value; f32 rounding independent of association noise).
// ---------------------------------------------------------------------------
template<int CPT, bool PMAJOR>
__global__ __launch_bounds__(256) void gemmL_k(int P, int I, int xrs, int ld,
    const float* __restrict__ Xf, const float* __restrict__ W,
    const float* __restrict__ bias, float* __restrict__ out)
{
    __shared__ double xs[16][18];              // [row][p], padded (16B-align b128)
    __shared__ float  wt[CPT * 256][18];       // [col][p], padded
    int tid = threadIdx.x;
    int n0 = blockIdx.y * 16;
    int i0 = blockIdx.x * (CPT * 256);
    double acc[CPT][16];
#pragma unroll
    for (int s = 0; s < CPT; s++)
#pragma unroll
        for (int r = 0; r < 16; r++) acc[s][r] = 0.0;

    int nch = P / PC;
    for (int c = 0; c < nch; c++) {
        int p0 = c * PC;
        __syncthreads();
        // stage X: 16 rows x 16 p (1 elem/thread, coalesced within row)
        {
            int r = tid >> 4, p = tid & 15;
            xs[r][p] = (double)Xf[(size_t)(n0 + r) * xrs + p0 + p];
        }
        if (PMAJOR) {
            // W[p*ld + i]: stage along i (contiguous) with float4
            const int LPR = CPT * 64;          // float4 lanes per p-row
            const int RPI = 256 / LPR;         // p-rows per iteration
            int i4 = (tid % LPR) * 4;
            int pl = tid / LPR;
#pragma unroll
            for (int it = 0; it < PC / RPI; ++it) {
                int p = pl + it * RPI;
                int gi = i0 + i4;
                f32x4 v = {0.f, 0.f, 0.f, 0.f};
                if (gi + 3 < I) {
                    v = *(const f32x4*)&W[(size_t)(p0 + p) * ld + gi];
                } else {
#pragma unroll
                    for (int q = 0; q < 4; q++)
                        if (gi + q < I) v[q] = W[(size_t)(p0 + p) * ld + gi + q];
                }
                wt[i4 + 0][p] = v[0]; wt[i4 + 1][p] = v[1];
                wt[i4 + 2][p] = v[2]; wt[i4 + 3][p] = v[3];
            }
        } else {
            // W[i*ld + p]: stage along p (contiguous) with float4
            int p4 = (tid & 3) * 4;
            int il = tid >> 2;                 // 64 i-rows per iteration
#pragma unroll
            for (int it = 0; it < CPT * 4; ++it) {
                int i_loc = il + it * 64;
                long long gi = i0 + i_loc;
                if (gi >= I) gi = I - 1;       // clamp (stores are col-guarded)
                f32x4 v = *(const f32x4*)&W[(size_t)gi * ld + p0 + p4];
                wt[i_loc][p4 + 0] = v[0]; wt[i_loc][p4 + 1] = v[1];
                wt[i_loc][p4 + 2] = v[2]; wt[i_loc][p4 + 3] = v[3];
            }
        }
        __syncthreads();
        // compute: per 2p -> CPT f32x2 W reads + 16 broadcast b128 X reads + 32*CPT f64 FMA
#pragma unroll
        for (int p2 = 0; p2 < PC; p2 += 2) {
            f32x2 wv[CPT];
#pragma unroll
            for (int s = 0; s < CPT; s++)
                wv[s] = *(const f32x2*)&wt[s * 256 + tid][p2];
#pragma unroll
            for (int r = 0; r < 16; r++) {
                f64x2 xv = *(const f64x2*)&xs[r][p2];
#pragma unroll
                for (int s = 0; s < CPT; s++) {
                    acc[s][r] = ::fma(xv.x, (double)wv[s].x, acc[s][r]);
                    acc[s][r] = ::fma(xv.y, (double)wv[s].y, acc[s][r]);
                }
            }
        }
    }
#pragma unroll
    for (int s = 0; s < CPT; s++) {
        int cs = i0 + s * 256 + tid;
        if (cs < I) {
            float bv = bias ? bias[cs] : 0.f;
#pragma unroll
            for (int r = 0; r < 16; r++) {
                float v = (float)acc[s][r];      // round true sum to f32
                if (bias) v = __fadd_rn(v, bv);  // then f32 bias add (as ref)
                out[(size_t)(n0 + r) * I + cs] = v;
            }
        }
    }
}

// gather parent hidden + token embedding (all f32)
__global__ __launch_bounds__(256) void gather_k(int N, int Kcur,
    const int* __restrict__ maps, const int* __restrict__ toks,
    const float* __restrict__ h_beam, const float* __restrict__ E,
    float* __restrict__ h_g, float* __restrict__ xbuf)
{
    int n = blockIdx.x;
    if (n >= N) return;
    int b = n / Kcur;
    int tok = toks ? toks[n] : SEPTOK;
    const float* er = E + (size_t)tok * Hdim;
    if (maps) {
        const float* hs = h_beam + (size_t)(b * Kb + maps[n]) * Hdim;
        for (int j = threadIdx.x; j < Hdim; j += 256) {
            h_g[(size_t)n * Hdim + j]  = hs[j];
            xbuf[(size_t)n * 1536 + j] = er[j];
        }
    } else {
        for (int j = threadIdx.x; j < Hdim; j += 256) {
            h_g[(size_t)n * Hdim + j]  = 0.f;
            xbuf[(size_t)n * 1536 + j] = er[j];
        }
    }
}

// step-0 broadcast: h_beam[b,k,:] = h_tmp[b,:]
__global__ __launch_bounds__(256) void bcast_k(const float* __restrict__ h_tmp,
                                               float* __restrict__ h_beam)
{
    int b = blockIdx.x;
    for (int j = threadIdx.x; j < Hdim; j += 256) {
        float v = h_tmp[(size_t)b * Hdim + j];
        for (int k = 0; k < Kb; k++)
            h_beam[(size_t)(b * Kb + k) * Hdim + j] = v;
    }
}

// attention: e = tanh(srcWa + hUa) @ va; softmax over S; ctx -> xbuf[768:]
__global__ __launch_bounds__(256) void attn2_k(int N, int Kcur,
    const float* __restrict__ hUa, const float* __restrict__ srcWa,
    const float* __restrict__ src, const float* __restrict__ va,
    float* __restrict__ xbuf)
{
    __shared__ float hu[Hdim];
    __shared__ float va_s[Hdim];
    __shared__ float e_s[Ss];
    __shared__ float a_s[Ss];
    int n = blockIdx.x, tid = threadIdx.x;
    if (n >= N) return;
    int b = n / Kcur;
    for (int j = tid; j < Hdim; j += 256) {
        hu[j]   = hUa[(size_t)n * Hdim + j];
        va_s[j] = va[j];
    }
    __syncthreads();
    int wv = tid >> 6, ln = tid & 63;
    for (int s = wv * 16; s < wv * 16 + 16; s++) {
        const float* sw = srcWa + (size_t)(b * Ss + s) * Hdim;
        double p = 0.0;
        for (int j = ln; j < Hdim; j += 64) {
            float tv = (float)tanh((double)__fadd_rn(sw[j], hu[j]));
            p = ::fma((double)tv, (double)va_s[j], p);
        }
        for (int off = 32; off; off >>= 1) p += __shfl_down(p, off, 64);
        if (ln == 0) e_s[s] = (float)p;
    }
    __syncthreads();
    if (tid < 64) {
        float v = e_s[tid], m = v;
        for (int off = 32; off; off >>= 1) m = fmaxf(m, __shfl_xor(m, off, 64));
        float p = (float)exp((double)__fsub_rn(v, m));
        double sum = (double)p;
        for (int off = 32; off; off >>= 1) sum += __shfl_xor(sum, off, 64);
        a_s[tid] = __fdiv_rn(p, (float)sum);
    }
    __syncthreads();
    for (int j = tid; j < Hdim; j += 256) {
        double acc = 0.0;
        for (int s = 0; s < Ss; s++)
            acc = ::fma((double)a_s[s], (double)src[(size_t)(b * Ss + s) * Hdim + j], acc);
        xbuf[(size_t)n * 1536 + 768 + j] = (float)acc;
    }
}

// GRU gates; transcendentals in double rounded to f32, f32 combine chain as ref
__global__ __launch_bounds__(256) void gate_k(int N,
    const float* __restrict__ gx, const float* __restrict__ gh,
    const float* __restrict__ h_g, float* __restrict__ h_out)
{
    int idx = blockIdx.x * 256 + threadIdx.x;
    if (idx >= N * Hdim) return;
    int n = idx / Hdim, i = idx - n * Hdim;
    const float* gxr = gx + (size_t)n * 2304;
    const float* ghr = gh + (size_t)n * 2304;
    float xr = gxr[i], xz = gxr[768 + i], xn = gxr[1536 + i];
    float hr = ghr[i], hz = ghr[768 + i], hn = ghr[1536 + i];
    float r  = (float)(1.0 / (1.0 + exp(-(double)__fadd_rn(xr, hr))));
    float z  = (float)(1.0 / (1.0 + exp(-(double)__fadd_rn(xz, hz))));
    float nn = (float)tanh((double)__fadd_rn(xn, __fmul_rn(r, hn)));
    float hv = h_g[(size_t)n * Hdim + i];
    float h2 = __fadd_rn(__fmul_rn(__fsub_rn(1.f, z), nn), __fmul_rn(z, hv));
    h_out[(size_t)n * Hdim + i] = h2;
}

// per-row max and l = f32(log(f32(sum of f32-rounded exp)))
__global__ __launch_bounds__(256) void lse_k(int N,
    const float* __restrict__ logits, float* __restrict__ mx, float* __restrict__ lgs)
{
    __shared__ float  redf[256];
    __shared__ double redd[256];
    int n = blockIdx.x, tid = threadIdx.x;
    const float* lg = logits + (size_t)n * Vv;
    float m = -INFINITY;
    for (int v = tid; v < Vv; v += 256) m = fmaxf(m, lg[v]);
    redf[tid] = m; __syncthreads();
    for (int off = 128; off; off >>= 1) {
        if (tid < off) redf[tid] = fmaxf(redf[tid], redf[tid + off]);
        __syncthreads();
    }
    m = redf[0];
    double s = 0.0;
    for (int v = tid; v < Vv; v += 256) {
        float ex = (float)exp((double)__fsub_rn(lg[v], m));
        s += (double)ex;
    }
    redd[tid] = s; __syncthreads();
    for (int off = 128; off; off >>= 1) {
        if (tid < off) redd[tid] += redd[tid + off];
        __syncthreads();
    }
    if (tid == 0) {
        mx[n] = m;
        float sf = (float)redd[0];
        lgs[n] = (float)log((double)sf);
    }
}

// ------------------------- top-k helpers -----------------------------------
__device__ __forceinline__ bool betterf(float va, int ja, float vb, int jb) {
    return (va > vb) || (va == vb && ja < jb);
}
__device__ __forceinline__ void ins5(float* tv, int* tj, float v, int j) {
    if (!betterf(v, j, tv[4], tj[4])) return;
    tv[4] = v; tj[4] = j;
#pragma unroll
    for (int q = 4; q > 0; q--) {
        if (betterf(tv[q], tj[q], tv[q - 1], tj[q - 1])) {
            float t = tv[q]; tv[q] = tv[q - 1]; tv[q - 1] = t;
            int  ti = tj[q]; tj[q] = tj[q - 1]; tj[q - 1] = ti;
        }
    }
}

// single scan with per-thread top-5, then 5-pass argmax over the LDS pool
__global__ __launch_bounds__(256) void topk5_k(int t,
    const float* __restrict__ logits, const float* __restrict__ mx, const float* __restrict__ lgs,
    float* scores, float* ended, float* lengths,
    int* toks_cur, int* maps_cur, int* toks_all, int* maps_all)
{
    __shared__ float sc_s[Kb], den_s[Kb], end_s[Kb], len_s[Kb], mx_s[Kb], lg_s[Kb];
    __shared__ float mv[256 * 5];
    __shared__ int   mj[256 * 5];
    __shared__ float rv[256];
    __shared__ int   rj[256];
    __shared__ int   selj[Kb];
    int b = blockIdx.x, tid = threadIdx.x;
    int Kcur = (t == 0) ? 1 : Kb;
    if (tid < Kb) {
        if (t == 0) {
            sc_s[tid] = 0.f; end_s[tid] = 0.f; len_s[tid] = 0.f; den_s[tid] = 1.f;
            mx_s[tid] = mx[b]; lg_s[tid] = lgs[b];
        } else {
            float e0 = ended[b * Kb + tid];
            float ln = __fadd_rn(lengths[b * Kb + tid], (e0 == 0.f) ? 1.f : 0.f);
            sc_s[tid]  = scores[b * Kb + tid];
            end_s[tid] = e0;
            len_s[tid] = ln;
            den_s[tid] = (tid < Kb - 1) ? (float)pow((double)ln, (double)0.7f) : 1.f;
            mx_s[tid]  = mx[b * Kb + tid];
            lg_s[tid]  = lgs[b * Kb + tid];
        }
    }
    __syncthreads();
    const float* lbase = logits + (size_t)b * Kcur * Vv;
    float tv[5]; int tj[5];
#pragma unroll
    for (int q = 0; q < 5; q++) { tv[q] = -INFINITY; tj[q] = 0x7fffffff; }
    for (int k = 0; k < Kcur; k++) {
        if (end_s[k] == 0.f) {
            float m = mx_s[k], l = lg_s[k], sck = sc_s[k], den = den_s[k];
            const float* lg = lbase + (size_t)k * Vv;
            for (int v = tid; v < Vv; v += 256) {
                float lp  = __fsub_rn(__fsub_rn(lg[v], m), l);
                float val = __fdiv_rn(__fadd_rn(lp, sck), den);
                ins5(tv, tj, val, k * Vv + v);
            }
        } else if (tid == 0) {
            float val = __fdiv_rn(sc_s[k], den_s[k]);
            ins5(tv, tj, val, k * Vv + SEPTOK);
        }
    }
#pragma unroll
    for (int q = 0; q < 5; q++) { mv[tid * 5 + q] = tv[q]; mj[tid * 5 + q] = tj[q]; }
    __syncthreads();
    for (int pass = 0; pass < Kb; pass++) {
        float bv = -INFINITY; int bj = 0x7fffffff;
#pragma unroll
        for (int q = 0; q < 5; q++) {
            float v = mv[tid * 5 + q]; int j = mj[tid * 5 + q];
            if (betterf(v, j, bv, bj)) { bv = v; bj = j; }
        }
        rv[tid] = bv; rj[tid] = bj;
        __syncthreads();
        for (int off = 128; off; off >>= 1) {
            if (tid < off) {
                float ov = rv[tid + off]; int oj = rj[tid + off];
                if (betterf(ov, oj, rv[tid], rj[tid])) { rv[tid] = ov; rj[tid] = oj; }
            }
            __syncthreads();
        }
        if (tid == 0) selj[pass] = rj[0];
        __syncthreads();
#pragma unroll
        for (int q = 0; q < 5; q++)
            if (mj[tid * 5 + q] == selj[pass]) { mv[tid * 5 + q] = -INFINITY; mj[tid * 5 + q] = 0x7fffffff; }
        __syncthreads();
    }
    if (tid == 0) {
        for (int q = 0; q < Kb; q++) {
            int jj = selj[q];
            int pk = jj / Vv, vv = jj - pk * Vv;
            float lp;
            if (end_s[pk] == 0.f)
                lp = __fsub_rn(__fsub_rn(lbase[(size_t)pk * Vv + vv], mx_s[pk]), lg_s[pk]);
            else
                lp = (vv == SEPTOK) ? 0.f : -1e9f;
            float cand = __fadd_rn(lp, sc_s[pk]);
            scores[b * Kb + q]   = cand;
            toks_cur[b * Kb + q] = vv;
            maps_cur[b * Kb + q] = (t == 0) ? 0 : pk;
            if (t == 0) {
                ended[b * Kb + q]   = 0.f;
                lengths[b * Kb + q] = 0.f;
            } else {
                ended[b * Kb + q]   = (vv == SEPTOK) ? 1.f : end_s[q];
                lengths[b * Kb + q] = len_s[q];
            }
            toks_all[(size_t)t * Bb * Kb + b * Kb + q] = vv;
            maps_all[(size_t)t * Bb * Kb + b * Kb + q] = (t == 0) ? 0 : pk;
        }
    }
}

__global__ void back_k(const float* __restrict__ scores,
                       const int* __restrict__ toks_all, const int* __restrict__ maps_all,
                       int* __restrict__ out)
{
    int b = threadIdx.x;
    if (b >= Bb) return;
    int best = 0; float bvv = scores[b * Kb];
    for (int k = 1; k < Kb; k++) {
        float v = scores[b * Kb + k];
        if (v > bvv) { bvv = v; best = k; }
    }
    int cur = best;
    for (int t = Tt - 1; t >= 0; t--) {
        out[b * Tt + t] = toks_all[t * Bb * Kb + b * Kb + cur];
        cur = maps_all[t * Bb * Kb + b * Kb + cur];
    }
}

// ---------------------------------------------------------------------------
extern "C" void kernel_launch(void* const* d_in, const int* in_sizes, int n_in,
                              void* d_out, int out_size, void* d_ws, size_t ws_size,
                              hipStream_t stream)
{
    const float* src  = (const float*)d_in[0];
    const float* E    = (const float*)d_in[1];
    const float* Wa   = (const float*)d_in[2];
    const float* Ua   = (const float*)d_in[3];
    const float* va   = (const float*)d_in[4];
    const float* W_ih = (const float*)d_in[5];
    const float* W_hh = (const float*)d_in[6];
    const float* b_ih = (const float*)d_in[7];
    const float* b_hh = (const float*)d_in[8];
    const float* Wo   = (const float*)d_in[9];
    const float* bo   = (const float*)d_in[10];
    int* out = (int*)d_out;

    char* w = (char*)d_ws;
    size_t used = 0;
    auto alloc = [&](size_t bytes) -> char* {
        char* p = w + used;
        used += (bytes + 255) & ~(size_t)255;
        return p;
    };
    float*  srcWa   = (float*) alloc((size_t)Bb * Ss * Hdim * 4);
    float*  h_beam  = (float*) alloc((size_t)Bb * Kb * Hdim * 4);
    float*  h_tmp   = (float*) alloc((size_t)Bb * Hdim * 4);
    float*  h_g     = (float*) alloc((size_t)Bb * Kb * Hdim * 4);
    float*  hUa     = (float*) alloc((size_t)Bb * Kb * Hdim * 4);
    float*  xbuf    = (float*) alloc((size_t)Bb * Kb * 1536 * 4);
    float*  gx      = (float*) alloc((size_t)Bb * Kb * 2304 * 4);
    float*  gh      = (float*) alloc((size_t)Bb * Kb * 2304 * 4);
    float*  logits  = (float*) alloc((size_t)Bb * Kb * Vv * 4);
    float*  mx      = (float*) alloc(Bb * Kb * 4);
    float*  lgs     = (float*) alloc(Bb * Kb * 4);
    float*  scores  = (float*) alloc(Bb * Kb * 4);
    float*  ended   = (float*) alloc(Bb * Kb * 4);
    float*  lengths = (float*) alloc(Bb * Kb * 4);
    int* toks_cur = (int*)alloc(Bb * Kb * 4);
    int* maps_cur = (int*)alloc(Bb * Kb * 4);
    int* toks_all = (int*)alloc((size_t)Tt * Bb * Kb * 4);
    int* maps_all = (int*)alloc((size_t)Tt * Bb * Kb * 4);

    // srcWa = src @ Wa : Wa is [p][i] (p-major), N = B*S = 2048
    gemmL_k<2, true><<<dim3(2, (Bb * Ss) / 16), 256, 0, stream>>>(
        Hdim, Hdim, Hdim, Hdim, src, Wa, nullptr, srcWa);

    for (int t = 0; t < Tt; t++) {
        int N  = (t == 0) ? Bb : Bb * Kb;
        int Kc = (t == 0) ? 1 : Kb;
        const int* mp = (t == 0) ? nullptr : maps_cur;
        const int* tk = (t == 0) ? nullptr : toks_cur;
        float* h_cur = (t == 0) ? h_tmp : h_beam;
        int nrt = N / 16;

        gather_k<<<N, 256, 0, stream>>>(N, Kc, mp, tk, h_beam, E, h_g, xbuf);
        // h @ Ua : Ua is [p][i] (p-major)
        gemmL_k<2, true><<<dim3(2, nrt), 256, 0, stream>>>(
            Hdim, Hdim, Hdim, Hdim, h_g, Ua, nullptr, hUa);
        attn2_k<<<N, 256, 0, stream>>>(N, Kc, hUa, srcWa, src, va, xbuf);
        // x @ W_ih.T : W_ih is [i][p] = [2304][1536] (i-major)
        gemmL_k<2, false><<<dim3(5, nrt), 256, 0, stream>>>(
            1536, 2304, 1536, 1536, xbuf, W_ih, b_ih, gx);
        // h @ W_hh.T : W_hh is [i][p] = [2304][768]
        gemmL_k<2, false><<<dim3(5, nrt), 256, 0, stream>>>(
            Hdim, 2304, Hdim, Hdim, h_g, W_hh, b_hh, gh);
        gate_k<<<(N * Hdim + 255) / 256, 256, 0, stream>>>(N, gx, gh, h_g, h_cur);
        if (t == 0)
            bcast_k<<<Bb, 256, 0, stream>>>(h_tmp, h_beam);
        // h2 @ Wo.T : Wo is [i][p] = [30522][768]; 30 col-blocks x nrt
        gemmL_k<4, false><<<dim3(30, nrt), 256, 0, stream>>>(
            Hdim, Vv, Hdim, Hdim, h_cur, Wo, bo, logits);
        lse_k<<<N, 256, 0, stream>>>(N, logits, mx, lgs);
        topk5_k<<<Bb, 256, 0, stream>>>(t, logits, mx, lgs, scores, ended, lengths,
                                        toks_cur, maps_cur, toks_all, maps_all);
    }
    back_k<<<1, 64, 0, stream>>>(scores, toks_all, maps_all, out);
}

// Round 7
// 49876.950 us; speedup vs baseline: 2.1602x; 2.1602x over previous
//
#include <hip/hip_runtime.h>
#include <cmath>
#include <cfloat>

#define Hdim 768
#define Bb 32
#define Kb 5
#define Ss 64
#define Vv 30522
#define Tt 40
#define SEPTOK 102
#define PC 16

typedef __attribute__((ext_vector_type(2))) float  f32x2;
typedef __attribute__((ext_vector_type(4))) float  f32x4;

// ---------------------------------------------------------------------------
// f32 GEMM, LDS-staged X + LDS-transposed W tile, two-level accumulation:
//   out[n,i] = f32 chunked-sum_p X[n*xrs+p] * W_elem(p,i)  (+bias, f32)
// W_elem(p,i) = PMAJOR ? W[p*ld + i] : W[i*ld + p]  (both staged COALESCED).
// Block: 256 thr, tile = 16 rows x (256*CPT) cols, K-chunk = PC(16).
// Accumulation: 16-term chunk partial (registers) added to running acc ->
// error ~16-64 ulp, below the np reference's own sequential-f32 noise.
// N multiple of 16; P multiple of 16.
// ---------------------------------------------------------------------------
template<int CPT, bool PMAJOR>
__global__ __launch_bounds__(256) void gemmF_k(int P, int I, int xrs, int ld,
    const float* __restrict__ Xf, const float* __restrict__ W,
    const float* __restrict__ bias, float* __restrict__ out)
{
    __shared__ float xs[16][18];               // [row][p], padded
    __shared__ float wt[CPT * 256][18];        // [col][p], padded
    int tid = threadIdx.x;
    int n0 = blockIdx.y * 16;
    int i0 = blockIdx.x * (CPT * 256);
    float acc[CPT][16];
#pragma unroll
    for (int s = 0; s < CPT; s++)
#pragma unroll
        for (int r = 0; r < 16; r++) acc[s][r] = 0.f;

    int nch = P / PC;
    for (int c = 0; c < nch; c++) {
        int p0 = c * PC;
        __syncthreads();
        // stage X: 16 rows x 16 p (1 elem/thread, coalesced within row)
        {
            int r = tid >> 4, p = tid & 15;
            xs[r][p] = Xf[(size_t)(n0 + r) * xrs + p0 + p];
        }
        if (PMAJOR) {
            // W[p*ld + i]: stage along i (contiguous) with float4
            const int LPR = CPT * 64;          // float4 lanes per p-row
            const int RPI = 256 / LPR;         // p-rows per iteration
            int i4 = (tid % LPR) * 4;
            int pl = tid / LPR;
#pragma unroll
            for (int it = 0; it < PC / RPI; ++it) {
                int p = pl + it * RPI;
                int gi = i0 + i4;
                f32x4 v = {0.f, 0.f, 0.f, 0.f};
                if (gi + 3 < I) {
                    v = *(const f32x4*)&W[(size_t)(p0 + p) * ld + gi];
                } else {
#pragma unroll
                    for (int q = 0; q < 4; q++)
                        if (gi + q < I) v[q] = W[(size_t)(p0 + p) * ld + gi + q];
                }
                wt[i4 + 0][p] = v[0]; wt[i4 + 1][p] = v[1];
                wt[i4 + 2][p] = v[2]; wt[i4 + 3][p] = v[3];
            }
        } else {
            // W[i*ld + p]: stage along p (contiguous) with float4
            int p4 = (tid & 3) * 4;
            int il = tid >> 2;                 // 64 i-rows per iteration
#pragma unroll
            for (int it = 0; it < CPT * 4; ++it) {
                int i_loc = il + it * 64;
                long long gi = i0 + i_loc;
                if (gi >= I) gi = I - 1;       // clamp (stores are col-guarded)
                f32x4 v = *(const f32x4*)&W[(size_t)gi * ld + p0 + p4];
                wt[i_loc][p4 + 0] = v[0]; wt[i_loc][p4 + 1] = v[1];
                wt[i_loc][p4 + 2] = v[2]; wt[i_loc][p4 + 3] = v[3];
            }
        }
        __syncthreads();
        // chunk partial in registers (two-level accumulation)
        float part[CPT][16];
#pragma unroll
        for (int s = 0; s < CPT; s++)
#pragma unroll
            for (int r = 0; r < 16; r++) part[s][r] = 0.f;
#pragma unroll
        for (int p2 = 0; p2 < PC; p2 += 2) {
            f32x2 wv[CPT];
#pragma unroll
            for (int s = 0; s < CPT; s++)
                wv[s] = *(const f32x2*)&wt[s * 256 + tid][p2];
#pragma unroll
            for (int r = 0; r < 16; r++) {
                f32x2 xv = *(const f32x2*)&xs[r][p2];
#pragma unroll
                for (int s = 0; s < CPT; s++) {
                    part[s][r] = fmaf(xv.x, wv[s].x, part[s][r]);
                    part[s][r] = fmaf(xv.y, wv[s].y, part[s][r]);
                }
            }
        }
#pragma unroll
        for (int s = 0; s < CPT; s++)
#pragma unroll
            for (int r = 0; r < 16; r++) acc[s][r] = __fadd_rn(acc[s][r], part[s][r]);
    }
#pragma unroll
    for (int s = 0; s < CPT; s++) {
        int cs = i0 + s * 256 + tid;
        if (cs < I) {
            float bv = bias ? bias[cs] : 0.f;
#pragma unroll
            for (int r = 0; r < 16; r++) {
                float v = acc[s][r];
                if (bias) v = __fadd_rn(v, bv);
                out[(size_t)(n0 + r) * I + cs] = v;
            }
        }
    }
}

// gather parent hidden + token embedding (all f32)
__global__ __launch_bounds__(256) void gather_k(int N, int Kcur,
    const int* __restrict__ maps, const int* __restrict__ toks,
    const float* __restrict__ h_beam, const float* __restrict__ E,
    float* __restrict__ h_g, float* __restrict__ xbuf)
{
    int n = blockIdx.x;
    if (n >= N) return;
    int b = n / Kcur;
    int tok = toks ? toks[n] : SEPTOK;
    const float* er = E + (size_t)tok * Hdim;
    if (maps) {
        const float* hs = h_beam + (size_t)(b * Kb + maps[n]) * Hdim;
        for (int j = threadIdx.x; j < Hdim; j += 256) {
            h_g[(size_t)n * Hdim + j]  = hs[j];
            xbuf[(size_t)n * 1536 + j] = er[j];
        }
    } else {
        for (int j = threadIdx.x; j < Hdim; j += 256) {
            h_g[(size_t)n * Hdim + j]  = 0.f;
            xbuf[(size_t)n * 1536 + j] = er[j];
        }
    }
}

// step-0 broadcast: h_beam[b,k,:] = h_tmp[b,:]
__global__ __launch_bounds__(256) void bcast_k(const float* __restrict__ h_tmp,
                                               float* __restrict__ h_beam)
{
    int b = blockIdx.x;
    for (int j = threadIdx.x; j < Hdim; j += 256) {
        float v = h_tmp[(size_t)b * Hdim + j];
        for (int k = 0; k < Kb; k++)
            h_beam[(size_t)(b * Kb + k) * Hdim + j] = v;
    }
}

// attention: e = tanh(srcWa + hUa) @ va; softmax over S; ctx -> xbuf[768:]
__global__ __launch_bounds__(256) void attn2_k(int N, int Kcur,
    const float* __restrict__ hUa, const float* __restrict__ srcWa,
    const float* __restrict__ src, const float* __restrict__ va,
    float* __restrict__ xbuf)
{
    __shared__ float hu[Hdim];
    __shared__ float va_s[Hdim];
    __shared__ float e_s[Ss];
    __shared__ float a_s[Ss];
    int n = blockIdx.x, tid = threadIdx.x;
    if (n >= N) return;
    int b = n / Kcur;
    for (int j = tid; j < Hdim; j += 256) {
        hu[j]   = hUa[(size_t)n * Hdim + j];
        va_s[j] = va[j];
    }
    __syncthreads();
    int wv = tid >> 6, ln = tid & 63;
    for (int s = wv * 16; s < wv * 16 + 16; s++) {
        const float* sw = srcWa + (size_t)(b * Ss + s) * Hdim;
        double p = 0.0;
        for (int j = ln; j < Hdim; j += 64) {
            float tv = (float)tanh((double)__fadd_rn(sw[j], hu[j]));
            p = ::fma((double)tv, (double)va_s[j], p);
        }
        for (int off = 32; off; off >>= 1) p += __shfl_down(p, off, 64);
        if (ln == 0) e_s[s] = (float)p;
    }
    __syncthreads();
    if (tid < 64) {
        float v = e_s[tid], m = v;
        for (int off = 32; off; off >>= 1) m = fmaxf(m, __shfl_xor(m, off, 64));
        float p = (float)exp((double)__fsub_rn(v, m));
        double sum = (double)p;
        for (int off = 32; off; off >>= 1) sum += __shfl_xor(sum, off, 64);
        a_s[tid] = __fdiv_rn(p, (float)sum);
    }
    __syncthreads();
    for (int j = tid; j < Hdim; j += 256) {
        double acc = 0.0;
        for (int s = 0; s < Ss; s++)
            acc = ::fma((double)a_s[s], (double)src[(size_t)(b * Ss + s) * Hdim + j], acc);
        xbuf[(size_t)n * 1536 + 768 + j] = (float)acc;
    }
}

// GRU gates; transcendentals in double rounded to f32, f32 combine chain as ref
__global__ __launch_bounds__(256) void gate_k(int N,
    const float* __restrict__ gx, const float* __restrict__ gh,
    const float* __restrict__ h_g, float* __restrict__ h_out)
{
    int idx = blockIdx.x * 256 + threadIdx.x;
    if (idx >= N * Hdim) return;
    int n = idx / Hdim, i = idx - n * Hdim;
    const float* gxr = gx + (size_t)n * 2304;
    const float* ghr = gh + (size_t)n * 2304;
    float xr = gxr[i], xz = gxr[768 + i], xn = gxr[1536 + i];
    float hr = ghr[i], hz = ghr[768 + i], hn = ghr[1536 + i];
    float r  = (float)(1.0 / (1.0 + exp(-(double)__fadd_rn(xr, hr))));
    float z  = (float)(1.0 / (1.0 + exp(-(double)__fadd_rn(xz, hz))));
    float nn = (float)tanh((double)__fadd_rn(xn, __fmul_rn(r, hn)));
    float hv = h_g[(size_t)n * Hdim + i];
    float h2 = __fadd_rn(__fmul_rn(__fsub_rn(1.f, z), nn), __fmul_rn(z, hv));
    h_out[(size_t)n * Hdim + i] = h2;
}

// per-row max and l = f32(log(f32(sum of f32-rounded exp)))
__global__ __launch_bounds__(256) void lse_k(int N,
    const float* __restrict__ logits, float* __restrict__ mx, float* __restrict__ lgs)
{
    __shared__ float  redf[256];
    __shared__ double redd[256];
    int n = blockIdx.x, tid = threadIdx.x;
    const float* lg = logits + (size_t)n * Vv;
    float m = -INFINITY;
    for (int v = tid; v < Vv; v += 256) m = fmaxf(m, lg[v]);
    redf[tid] = m; __syncthreads();
    for (int off = 128; off; off >>= 1) {
        if (tid < off) redf[tid] = fmaxf(redf[tid], redf[tid + off]);
        __syncthreads();
    }
    m = redf[0];
    double s = 0.0;
    for (int v = tid; v < Vv; v += 256) {
        float ex = (float)exp((double)__fsub_rn(lg[v], m));
        s += (double)ex;
    }
    redd[tid] = s; __syncthreads();
    for (int off = 128; off; off >>= 1) {
        if (tid < off) redd[tid] += redd[tid + off];
        __syncthreads();
    }
    if (tid == 0) {
        mx[n] = m;
        float sf = (float)redd[0];
        lgs[n] = (float)log((double)sf);
    }
}

// ------------------------- top-k helpers -----------------------------------
__device__ __forceinline__ bool betterf(float va, int ja, float vb, int jb) {
    return (va > vb) || (va == vb && ja < jb);
}
__device__ __forceinline__ void ins5(float* tv, int* tj, float v, int j) {
    if (!betterf(v, j, tv[4], tj[4])) return;
    tv[4] = v; tj[4] = j;
#pragma unroll
    for (int q = 4; q > 0; q--) {
        if (betterf(tv[q], tj[q], tv[q - 1], tj[q - 1])) {
            float t = tv[q]; tv[q] = tv[q - 1]; tv[q - 1] = t;
            int  ti = tj[q]; tj[q] = tj[q - 1]; tj[q - 1] = ti;
        }
    }
}

// single scan with per-thread top-5, then 5-pass argmax over the LDS pool
__global__ __launch_bounds__(256) void topk5_k(int t,
    const float* __restrict__ logits, const float* __restrict__ mx, const float* __restrict__ lgs,
    float* scores, float* ended, float* lengths,
    int* toks_cur, int* maps_cur, int* toks_all, int* maps_all)
{
    __shared__ float sc_s[Kb], den_s[Kb], end_s[Kb], len_s[Kb], mx_s[Kb], lg_s[Kb];
    __shared__ float mv[256 * 5];
    __shared__ int   mj[256 * 5];
    __shared__ float rv[256];
    __shared__ int   rj[256];
    __shared__ int   selj[Kb];
    int b = blockIdx.x, tid = threadIdx.x;
    int Kcur = (t == 0) ? 1 : Kb;
    if (tid < Kb) {
        if (t == 0) {
            sc_s[tid] = 0.f; end_s[tid] = 0.f; len_s[tid] = 0.f; den_s[tid] = 1.f;
            mx_s[tid] = mx[b]; lg_s[tid] = lgs[b];
        } else {
            float e0 = ended[b * Kb + tid];
            float ln = __fadd_rn(lengths[b * Kb + tid], (e0 == 0.f) ? 1.f : 0.f);
            sc_s[tid]  = scores[b * Kb + tid];
            end_s[tid] = e0;
            len_s[tid] = ln;
            den_s[tid] = (tid < Kb - 1) ? (float)pow((double)ln, (double)0.7f) : 1.f;
            mx_s[tid]  = mx[b * Kb + tid];
            lg_s[tid]  = lgs[b * Kb + tid];
        }
    }
    __syncthreads();
    const float* lbase = logits + (size_t)b * Kcur * Vv;
    float tv[5]; int tj[5];
#pragma unroll
    for (int q = 0; q < 5; q++) { tv[q] = -INFINITY; tj[q] = 0x7fffffff; }
    for (int k = 0; k < Kcur; k++) {
        if (end_s[k] == 0.f) {
            float m = mx_s[k], l = lg_s[k], sck = sc_s[k], den = den_s[k];
            const float* lg = lbase + (size_t)k * Vv;
            for (int v = tid; v < Vv; v += 256) {
                float lp  = __fsub_rn(__fsub_rn(lg[v], m), l);
                float val = __fdiv_rn(__fadd_rn(lp, sck), den);
                ins5(tv, tj, val, k * Vv + v);
            }
        } else if (tid == 0) {
            float val = __fdiv_rn(sc_s[k], den_s[k]);
            ins5(tv, tj, val, k * Vv + SEPTOK);
        }
    }
#pragma unroll
    for (int q = 0; q < 5; q++) { mv[tid * 5 + q] = tv[q]; mj[tid * 5 + q] = tj[q]; }
    __syncthreads();
    for (int pass = 0; pass < Kb; pass++) {
        float bv = -INFINITY; int bj = 0x7fffffff;
#pragma unroll
        for (int q = 0; q < 5; q++) {
            float v = mv[tid * 5 + q]; int j = mj[tid * 5 + q];
            if (betterf(v, j, bv, bj)) { bv = v; bj = j; }
        }
        rv[tid] = bv; rj[tid] = bj;
        __syncthreads();
        for (int off = 128; off; off >>= 1) {
            if (tid < off) {
                float ov = rv[tid + off]; int oj = rj[tid + off];
                if (betterf(ov, oj, rv[tid], rj[tid])) { rv[tid] = ov; rj[tid] = oj; }
            }
            __syncthreads();
        }
        if (tid == 0) selj[pass] = rj[0];
        __syncthreads();
#pragma unroll
        for (int q = 0; q < 5; q++)
            if (mj[tid * 5 + q] == selj[pass]) { mv[tid * 5 + q] = -INFINITY; mj[tid * 5 + q] = 0x7fffffff; }
        __syncthreads();
    }
    if (tid == 0) {
        for (int q = 0; q < Kb; q++) {
            int jj = selj[q];
            int pk = jj / Vv, vv = jj - pk * Vv;
            float lp;
            if (end_s[pk] == 0.f)
                lp = __fsub_rn(__fsub_rn(lbase[(size_t)pk * Vv + vv], mx_s[pk]), lg_s[pk]);
            else
                lp = (vv == SEPTOK) ? 0.f : -1e9f;
            float cand = __fadd_rn(lp, sc_s[pk]);
            scores[b * Kb + q]   = cand;
            toks_cur[b * Kb + q] = vv;
            maps_cur[b * Kb + q] = (t == 0) ? 0 : pk;
            if (t == 0) {
                ended[b * Kb + q]   = 0.f;
                lengths[b * Kb + q] = 0.f;
            } else {
                ended[b * Kb + q]   = (vv == SEPTOK) ? 1.f : end_s[q];
                lengths[b * Kb + q] = len_s[q];
            }
            toks_all[(size_t)t * Bb * Kb + b * Kb + q] = vv;
            maps_all[(size_t)t * Bb * Kb + b * Kb + q] = (t == 0) ? 0 : pk;
        }
    }
}

__global__ void back_k(const float* __restrict__ scores,
                       const int* __restrict__ toks_all, const int* __restrict__ maps_all,
                       int* __restrict__ out)
{
    int b = threadIdx.x;
    if (b >= Bb) return;
    int best = 0; float bvv = scores[b * Kb];
    for (int k = 1; k < Kb; k++) {
        float v = scores[b * Kb + k];
        if (v > bvv) { bvv = v; best = k; }
    }
    int cur = best;
    for (int t = Tt - 1; t >= 0; t--) {
        out[b * Tt + t] = toks_all[t * Bb * Kb + b * Kb + cur];
        cur = maps_all[t * Bb * Kb + b * Kb + cur];
    }
}

// ---------------------------------------------------------------------------
extern "C" void kernel_launch(void* const* d_in, const int* in_sizes, int n_in,
                              void* d_out, int out_size, void* d_ws, size_t ws_size,
                              hipStream_t stream)
{
    const float* src  = (const float*)d_in[0];
    const float* E    = (const float*)d_in[1];
    const float* Wa   = (const float*)d_in[2];
    const float* Ua   = (const float*)d_in[3];
    const float* va   = (const float*)d_in[4];
    const float* W_ih = (const float*)d_in[5];
    const float* W_hh = (const float*)d_in[6];
    const float* b_ih = (const float*)d_in[7];
    const float* b_hh = (const float*)d_in[8];
    const float* Wo   = (const float*)d_in[9];
    const float* bo   = (const float*)d_in[10];
    int* out = (int*)d_out;

    char* w = (char*)d_ws;
    size_t used = 0;
    auto alloc = [&](size_t bytes) -> char* {
        char* p = w + used;
        used += (bytes + 255) & ~(size_t)255;
        return p;
    };
    float*  srcWa   = (float*) alloc((size_t)Bb * Ss * Hdim * 4);
    float*  h_beam  = (float*) alloc((size_t)Bb * Kb * Hdim * 4);
    float*  h_tmp   = (float*) alloc((size_t)Bb * Hdim * 4);
    float*  h_g     = (float*) alloc((size_t)Bb * Kb * Hdim * 4);
    float*  hUa     = (float*) alloc((size_t)Bb * Kb * Hdim * 4);
    float*  xbuf    = (float*) alloc((size_t)Bb * Kb * 1536 * 4);
    float*  gx      = (float*) alloc((size_t)Bb * Kb * 2304 * 4);
    float*  gh      = (float*) alloc((size_t)Bb * Kb * 2304 * 4);
    float*  logits  = (float*) alloc((size_t)Bb * Kb * Vv * 4);
    float*  mx      = (float*) alloc(Bb * Kb * 4);
    float*  lgs     = (float*) alloc(Bb * Kb * 4);
    float*  scores  = (float*) alloc(Bb * Kb * 4);
    float*  ended   = (float*) alloc(Bb * Kb * 4);
    float*  lengths = (float*) alloc(Bb * Kb * 4);
    int* toks_cur = (int*)alloc(Bb * Kb * 4);
    int* maps_cur = (int*)alloc(Bb * Kb * 4);
    int* toks_all = (int*)alloc((size_t)Tt * Bb * Kb * 4);
    int* maps_all = (int*)alloc((size_t)Tt * Bb * Kb * 4);

    // srcWa = src @ Wa : Wa is [p][i] (p-major), N = B*S = 2048
    gemmF_k<1, true><<<dim3(3, (Bb * Ss) / 16), 256, 0, stream>>>(
        Hdim, Hdim, Hdim, Hdim, src, Wa, nullptr, srcWa);

    for (int t = 0; t < Tt; t++) {
        int N  = (t == 0) ? Bb : Bb * Kb;
        int Kc = (t == 0) ? 1 : Kb;
        const int* mp = (t == 0) ? nullptr : maps_cur;
        const int* tk = (t == 0) ? nullptr : toks_cur;
        float* h_cur = (t == 0) ? h_tmp : h_beam;
        int nrt = N / 16;

        gather_k<<<N, 256, 0, stream>>>(N, Kc, mp, tk, h_beam, E, h_g, xbuf);
        // h @ Ua : Ua is [p][i] (p-major)
        gemmF_k<1, true><<<dim3(3, nrt), 256, 0, stream>>>(
            Hdim, Hdim, Hdim, Hdim, h_g, Ua, nullptr, hUa);
        attn2_k<<<N, 256, 0, stream>>>(N, Kc, hUa, srcWa, src, va, xbuf);
        // x @ W_ih.T : W_ih is [i][p] = [2304][1536] (i-major)
        gemmF_k<1, false><<<dim3(9, nrt), 256, 0, stream>>>(
            1536, 2304, 1536, 1536, xbuf, W_ih, b_ih, gx);
        // h @ W_hh.T : W_hh is [i][p] = [2304][768]
        gemmF_k<1, false><<<dim3(9, nrt), 256, 0, stream>>>(
            Hdim, 2304, Hdim, Hdim, h_g, W_hh, b_hh, gh);
        gate_k<<<(N * Hdim + 255) / 256, 256, 0, stream>>>(N, gx, gh, h_g, h_cur);
        if (t == 0)
            bcast_k<<<Bb, 256, 0, stream>>>(h_tmp, h_beam);
        // h2 @ Wo.T : Wo is [i][p] = [30522][768]; 30 col-blocks x nrt
        gemmF_k<4, false><<<dim3(30, nrt), 256, 0, stream>>>(
            Hdim, Vv, Hdim, Hdim, h_cur, Wo, bo, logits);
        lse_k<<<N, 256, 0, stream>>>(N, logits, mx, lgs);
        topk5_k<<<Bb, 256, 0, stream>>>(t, logits, mx, lgs, scores, ended, lengths,
                                        toks_cur, maps_cur, toks_all, maps_all);
    }
    back_k<<<1, 64, 0, stream>>>(scores, toks_all, maps_all, out);
}